// Round 14
// baseline (44.843 us; speedup 1.0000x reference)
//
#include <hip/hip_runtime.h>

#define NEGV (-10000000000.0f)

typedef unsigned short u16;
typedef _Float16 __attribute__((ext_vector_type(8))) f16x8;
typedef _Float16 __attribute__((ext_vector_type(4))) f16x4;
typedef __attribute__((ext_vector_type(4))) float f32x4;

__device__ __forceinline__ u16 f2fh(float f) {
  _Float16 h = (_Float16)f;
  return __builtin_bit_cast(u16, h);
}

__device__ __forceinline__ void gload16(const u16* g, u16* l) {
  __builtin_amdgcn_global_load_lds(
      (const __attribute__((address_space(1))) void*)g,
      (__attribute__((address_space(3))) void*)l, 16, 0, 0);
}

__device__ __forceinline__ f16x8 cvt8(float4 x, float4 y) {
  f16x8 o;
  o[0] = (_Float16)x.x; o[1] = (_Float16)x.y;
  o[2] = (_Float16)x.z; o[3] = (_Float16)x.w;
  o[4] = (_Float16)y.x; o[5] = (_Float16)y.y;
  o[6] = (_Float16)y.z; o[7] = (_Float16)y.w;
  return o;
}

// ---------------------------------------------------------------------------
// 64x64 MFMA step (4 waves 2x2, 2x2 fragments). Rows = 128B of fp16, XOR
// swizzle byte ^= (row&7)<<4.
// ---------------------------------------------------------------------------
__device__ __forceinline__ void mfma_tile(const u16* sA, const u16* sB,
                                          int l, int wr, int wc,
                                          f32x4 (*acc)[2]) {
#pragma unroll
  for (int ks = 0; ks < 2; ks++) {
    f16x8 af[2], bfr[2];
#pragma unroll
    for (int f = 0; f < 2; f++) {
      int cb = (ks * 32 + ((l >> 4) << 3)) << 1;
      int row = wr * 32 + f * 16 + (l & 15);
      af[f] = *(const f16x8*)((const char*)sA + row * 128 + (cb ^ ((row & 7) << 4)));
      int col = wc * 32 + f * 16 + (l & 15);
      bfr[f] = *(const f16x8*)((const char*)sB + col * 128 + (cb ^ ((col & 7) << 4)));
    }
#pragma unroll
    for (int fm = 0; fm < 2; fm++)
#pragma unroll
      for (int fn = 0; fn < 2; fn++)
        acc[fm][fn] = __builtin_amdgcn_mfma_f32_16x16x32_f16(
            af[fm], bfr[fn], acc[fm][fn], 0, 0, 0);
  }
}

// 128x128 MFMA step (4 waves 2x2, each 64x64 = 4x4 fragments).
__device__ __forceinline__ void mfma_tile128(const u16* sA, const u16* sB,
                                             int l, int wr, int wc,
                                             f32x4 (*acc)[4]) {
#pragma unroll
  for (int ks = 0; ks < 2; ks++) {
    f16x8 af[4], bfr[4];
#pragma unroll
    for (int f = 0; f < 4; f++) {
      int cb = (ks * 32 + ((l >> 4) << 3)) << 1;
      int row = wr * 64 + f * 16 + (l & 15);
      af[f] = *(const f16x8*)((const char*)sA + row * 128 + (cb ^ ((row & 7) << 4)));
      int col = wc * 64 + f * 16 + (l & 15);
      bfr[f] = *(const f16x8*)((const char*)sB + col * 128 + (cb ^ ((col & 7) << 4)));
    }
#pragma unroll
    for (int fm = 0; fm < 4; fm++)
#pragma unroll
      for (int fn = 0; fn < 4; fn++)
        acc[fm][fn] = __builtin_amdgcn_mfma_f32_16x16x32_f16(
            af[fm], bfr[fn], acc[fm][fn], 0, 0, 0);
  }
}

// ---------------------------------------------------------------------------
// dispatch 1: proj, XCD-swizzled (128 = 8x16, bijective).
//   ids 0..63 : qpE = exp(2(query·Wq^T + b))  -- 64x64 tiles, masked-q skip
//   ids 64..127: kpE = exp(2(Wk·kv[b]^T))     -- 128x128 tiles (kv read 2x,
//                Wk 4x instead of 4x/8x), masked-k skip
// f32 inputs staged through registers, converted fp16, swizzled LDS, MFMA.
// ---------------------------------------------------------------------------
__global__ __launch_bounds__(256) void proj_mfma(
    const float* __restrict__ query, const float* __restrict__ kv,
    const float* __restrict__ W, const float* __restrict__ bias,
    const int* __restrict__ qlen_p, const int* __restrict__ klen_p,
    float* __restrict__ qpE, float* __restrict__ kpE)
{
  __shared__ __align__(16) u16 smem[2 * 128 * 64];   // 32KB
  u16* sA = smem;
  u16* sB = smem + 128 * 64;

  const int p = blockIdx.x;
  const int id = (p & 7) * 16 + (p >> 3);
  const int t = threadIdx.x;
  const int l = t & 63, w = t >> 6;
  const int wr = w >> 1, wc = w & 1;

  if (id < 64) {
    // ---------------- qp: 64x64 ----------------
    const int bm = (id >> 2) * 64, bn = (id & 3) * 64;
    if ((bm & 127) >= qlen_p[bm >> 7]) return;

    const float* A = query;                 // lda 512
    const float* B = W;                     // ldb 1024
    float* C = qpE;                         // ldc 256

    const int r0 = t >> 3, oc = t & 7;
    const int sw0 = (oc * 16) ^ ((r0 & 7) << 4);

    f32x4 acc[2][2] = {};
    float4 a00, a01, a10, a11, b00, b01, b10, b11;

    auto LOAD = [&](int k0) {
      const float* pa0 = A + (size_t)(bm + r0) * 512 + k0 + oc * 8;
      const float* pa1 = pa0 + (size_t)32 * 512;
      a00 = *(const float4*)pa0; a01 = *(const float4*)(pa0 + 4);
      a10 = *(const float4*)pa1; a11 = *(const float4*)(pa1 + 4);
      const float* pb0 = B + (size_t)(bn + r0) * 1024 + k0 + oc * 8;
      const float* pb1 = pb0 + (size_t)32 * 1024;
      b00 = *(const float4*)pb0; b01 = *(const float4*)(pb0 + 4);
      b10 = *(const float4*)pb1; b11 = *(const float4*)(pb1 + 4);
    };
    auto WRITE = [&]() {
      *(f16x8*)((char*)sA + r0 * 128 + sw0)        = cvt8(a00, a01);
      *(f16x8*)((char*)sA + (r0 + 32) * 128 + sw0) = cvt8(a10, a11);
      *(f16x8*)((char*)sB + r0 * 128 + sw0)        = cvt8(b00, b01);
      *(f16x8*)((char*)sB + (r0 + 32) * 128 + sw0) = cvt8(b10, b11);
    };

    LOAD(0);
    for (int k0 = 0; k0 < 512; k0 += 64) {
      __syncthreads();
      WRITE();
      if (k0 + 64 < 512) LOAD(k0 + 64);
      __syncthreads();
      mfma_tile(sA, sB, l, wr, wc, acc);
    }

#pragma unroll
    for (int fm = 0; fm < 2; fm++)
#pragma unroll
      for (int fn = 0; fn < 2; fn++) {
        int cn = bn + wc * 32 + fn * 16 + (l & 15);
        float bv = bias[cn];
#pragma unroll
        for (int j = 0; j < 4; j++) {
          int rm = bm + wr * 32 + fm * 16 + (l >> 4) * 4 + j;
          C[(size_t)rm * 256 + cn] = __expf((acc[fm][fn][j] + bv) * 2.0f);
        }
      }
  } else {
    // ---------------- kp: 128x128 ----------------
    const int r = id - 64;
    const int b = r >> 3, w5 = r & 7;
    const int bm = (w5 & 1) * 128;          // a-tile
    const int bn = (w5 >> 1) * 128;         // k-tile
    if (bn >= klen_p[b]) return;

    const float* A = W + 512;                           // Wk, lda 1024
    const float* B = kv + (size_t)b * 512 * 512;        // ldb 512
    float* C = kpE + (size_t)b * 256 * 512;             // ldc 512

    const int r0 = t >> 3, oc = t & 7;
    const int sw0 = (oc * 16) ^ ((r0 & 7) << 4);

    f32x4 acc[4][4] = {};
    float4 av[4][2], bv[4][2];

    auto LOAD = [&](int k0) {
#pragma unroll
      for (int i = 0; i < 4; i++) {
        const float* pa = A + (size_t)(bm + r0 + 32 * i) * 1024 + k0 + oc * 8;
        av[i][0] = *(const float4*)pa; av[i][1] = *(const float4*)(pa + 4);
        const float* pb = B + (size_t)(bn + r0 + 32 * i) * 512 + k0 + oc * 8;
        bv[i][0] = *(const float4*)pb; bv[i][1] = *(const float4*)(pb + 4);
      }
    };
    auto WRITE = [&]() {
#pragma unroll
      for (int i = 0; i < 4; i++) {
        *(f16x8*)((char*)sA + (r0 + 32 * i) * 128 + sw0) = cvt8(av[i][0], av[i][1]);
        *(f16x8*)((char*)sB + (r0 + 32 * i) * 128 + sw0) = cvt8(bv[i][0], bv[i][1]);
      }
    };

    LOAD(0);
    for (int k0 = 0; k0 < 512; k0 += 64) {
      __syncthreads();
      WRITE();
      if (k0 + 64 < 512) LOAD(k0 + 64);
      __syncthreads();
      mfma_tile128(sA, sB, l, wr, wc, acc);
    }

#pragma unroll
    for (int fm = 0; fm < 4; fm++)
#pragma unroll
      for (int fn = 0; fn < 4; fn++) {
        int cn = bn + wc * 64 + fn * 16 + (l & 15);
#pragma unroll
        for (int j = 0; j < 4; j++) {
          int rm = bm + wr * 64 + fm * 16 + (l >> 4) * 4 + j;
          C[(size_t)rm * 512 + cn] = __expf(acc[fm][fn][j] * 2.0f);
        }
      }
  }
}

// ---------------------------------------------------------------------------
// dispatch 2: fused score + softmax. 256 blocks XCD-swizzled (batch -> XCD).
// Block = 4 q rows x full 512 k (512 threads; lane owns k = t).
// score'[q,k] = -sum_a 2 v_a / (1 + eq[q][a]*ek[a][k]) (softmax-equivalent).
// P fp16: masked q -> uniform 1/512; k>=klen -> exact 0.
// ---------------------------------------------------------------------------
__global__ __launch_bounds__(512) void score_softmax(
    const float* __restrict__ qpE,    // [B*128][256] = exp(2(qp+b))
    const float* __restrict__ kpE,    // [B][256][512] = exp(2kp)
    const float* __restrict__ v,      // [256]
    const int* __restrict__ qlen_p, const int* __restrict__ klen_p,
    u16* __restrict__ P)              // [B][128][512] fp16
{
  const int p = blockIdx.x;
  const int log = (p & 7) * 32 + (p >> 3);
  const int b = log >> 5, q0 = (log & 31) * 4;
  const int t = threadIdx.x;
  const int qlen = qlen_p[b], klen = klen_p[b];
  const int w = t >> 6, l = t & 63;
  const int k = t;
  u16* Pb = P + (size_t)(b * 128 + q0) * 512;

  if (q0 >= qlen) {                   // all 4 rows masked -> uniform 1/512
    const u16 uh = f2fh(1.0f / 512.0f);
#pragma unroll
    for (int r = 0; r < 4; r++) Pb[(size_t)r * 512 + k] = uh;
    return;
  }

  __shared__ float sEq[256][4];
  __shared__ float sV2[256];
  __shared__ float sRed[8][8];

  {
    int a = t & 255, rr = t >> 8;
    sEq[a][rr]     = qpE[(size_t)(b * 128 + q0 + rr) * 256 + a];
    sEq[a][rr + 2] = qpE[(size_t)(b * 128 + q0 + rr + 2) * 256 + a];
    if (t < 256) sV2[t] = 2.0f * v[t];
  }
  __syncthreads();

  float s[4] = {0.f, 0.f, 0.f, 0.f};
  if (w * 64 < klen) {
    const float* kc = kpE + (size_t)b * 256 * 512 + k;
#pragma unroll 8
    for (int a = 0; a < 256; a++) {
      float ek = kc[(size_t)a * 512];
      f32x4 eq = *(const f32x4*)&sEq[a][0];
      float vv = sV2[a];
#pragma unroll
      for (int r = 0; r < 4; r++)
        s[r] = fmaf(-vv, __builtin_amdgcn_rcpf(fmaf(eq[r], ek, 1.0f)), s[r]);
    }
  }
  if (k >= klen) {
#pragma unroll
    for (int r = 0; r < 4; r++) s[r] = NEGV;
  }

#pragma unroll
  for (int r = 0; r < 4; r++) {
    float x = s[r];
#pragma unroll
    for (int off = 32; off > 0; off >>= 1) x = fmaxf(x, __shfl_xor(x, off));
    if (l == 0) sRed[w][r] = x;
  }
  __syncthreads();
  float e[4];
#pragma unroll
  for (int r = 0; r < 4; r++) {
    float mm = fmaxf(fmaxf(sRed[0][r], sRed[1][r]),
                     fmaxf(sRed[2][r], sRed[3][r]));
    mm = fmaxf(mm, fmaxf(fmaxf(sRed[4][r], sRed[5][r]),
                         fmaxf(sRed[6][r], sRed[7][r])));
    e[r] = __expf(s[r] - mm);
  }
  __syncthreads();
#pragma unroll
  for (int r = 0; r < 4; r++) {
    float x = e[r];
#pragma unroll
    for (int off = 32; off > 0; off >>= 1) x += __shfl_xor(x, off);
    if (l == 0) sRed[w][4 + r] = x;
  }
  __syncthreads();

  const u16 uh = f2fh(1.0f / 512.0f);
#pragma unroll
  for (int r = 0; r < 4; r++) {
    float S = (sRed[0][4 + r] + sRed[1][4 + r]) +
              (sRed[2][4 + r] + sRed[3][4 + r]) +
              (sRed[4][4 + r] + sRed[5][4 + r]) +
              (sRed[6][4 + r] + sRed[7][4 + r]);
    float pp = e[r] * __fdividef(1.0f, S);
    Pb[(size_t)r * 512 + k] = (q0 + r < qlen) ? f2fh(pp) : uh;
  }
}

// ---------------------------------------------------------------------------
// dispatch 3: pv. out[b] = P[b](fp16) @ kv[b](f32). 128 blocks XCD-swizzled
// (one batch per XCD). kv tile transposed to [d][k] fp16 in LDS during
// staging; P staged via global_load_lds. k-loop trimmed to ceil(klen/64)*64
// when the block's 64 q-rows are all active (P beyond klen is exact 0);
// blocks containing masked q rows (uniform P) keep the full 512 loop.
// ---------------------------------------------------------------------------
__global__ __launch_bounds__(256) void pv_mfma(
    const u16* __restrict__ P, const float* __restrict__ kv,
    const int* __restrict__ qlen_p, const int* __restrict__ klen_p,
    float* __restrict__ out)
{
  __shared__ __align__(16) u16 sA[8 * 512];
  __shared__ __align__(16) u16 sB[8 * 512];
  const int p = blockIdx.x;
  const int log = (p & 7) * 16 + (p >> 3);
  const int t = threadIdx.x;
  const int b = log >> 4, r = log & 15;
  const int bm = (r >> 3) * 64, bn = (r & 7) * 64;

  const int qlen = qlen_p[b], klen = klen_p[b];
  const int nk = (bm + 64 <= qlen) ? ((klen + 63) & ~63) : 512;

  const u16* Ab = P + (size_t)b * 128 * 512;
  const float* Bb = kv + (size_t)b * 512 * 512;

  const int l = t & 63, w = t >> 6;
  const int wr = w >> 1, wc = w & 1;
  const int srow = l >> 3, scol = ((l & 7) ^ srow) << 3;

  const int dq = t & 15, kq = t >> 4;

  float4 v0, v1, v2, v3;
  auto LOADB = [&](int k0) {
    const float* pp = Bb + (size_t)(k0 + kq * 4) * 512 + bn + dq * 4;
    v0 = *(const float4*)pp;
    v1 = *(const float4*)(pp + 512);
    v2 = *(const float4*)(pp + 1024);
    v3 = *(const float4*)(pp + 1536);
  };
  auto WRITEB = [&]() {
#define WRB(jj, ee)                                                       \
    { int d = dq * 4 + jj;                                                \
      f16x4 c; c[0] = (_Float16)v0.ee; c[1] = (_Float16)v1.ee;            \
      c[2] = (_Float16)v2.ee; c[3] = (_Float16)v3.ee;                     \
      *(f16x4*)((char*)sB + d * 128 +                                     \
                ((((kq >> 1) * 16) ^ ((d & 7) << 4)) + (kq & 1) * 8)) = c; }
    WRB(0, x) WRB(1, y) WRB(2, z) WRB(3, w)
#undef WRB
  };

  f32x4 acc[2][2] = {};
  LOADB(0);
  for (int k0 = 0; k0 < nk; k0 += 64) {
    __syncthreads();
    WRITEB();
#pragma unroll
    for (int i = 0; i < 2; i++) {
      int s = w * 2 + i;
      gload16(Ab + (size_t)(bm + s * 8 + srow) * 512 + k0 + scol, sA + s * 512);
    }
    if (k0 + 64 < nk) LOADB(k0 + 64);
    __syncthreads();
    mfma_tile(sA, sB, l, wr, wc, acc);
  }

  float* Cb = out + (size_t)b * 128 * 512;
#pragma unroll
  for (int fm = 0; fm < 2; fm++)
#pragma unroll
    for (int fn = 0; fn < 2; fn++) {
      int cn = bn + wc * 32 + fn * 16 + (l & 15);
#pragma unroll
      for (int j = 0; j < 4; j++) {
        int rm = bm + wr * 32 + fm * 16 + (l >> 4) * 4 + j;
        Cb[(size_t)rm * 512 + cn] = acc[fm][fn][j];
      }
    }
}

// ---------------------------------------------------------------------------
extern "C" void kernel_launch(void* const* d_in, const int* in_sizes, int n_in,
                              void* d_out, int out_size, void* d_ws, size_t ws_size,
                              hipStream_t stream)
{
  const float* query = (const float*)d_in[0];  // [8][128][512]
  const float* kv    = (const float*)d_in[1];  // [8][512][512]
  const float* W     = (const float*)d_in[2];  // [256][1024]
  const float* bbias = (const float*)d_in[3];  // [256]
  const float* v     = (const float*)d_in[4];  // [256]
  const int*   qlen  = (const int*)d_in[5];    // [8]
  const int*   klen  = (const int*)d_in[6];    // [8]
  float* out = (float*)d_out;                  // [8][128][512]

  float* qpE = (float*)d_ws;                   // 1MB
  float* kpE = qpE + 1024 * 256;               // 4MB
  u16*   P   = (u16*)(kpE + 8 * 256 * 512);    // 1MB

  proj_mfma<<<dim3(128), 256, 0, stream>>>(
      query, kv, W, bbias, qlen, klen, qpE, kpE);

  score_softmax<<<dim3(256), 512, 0, stream>>>(
      qpE, kpE, v, qlen, klen, P);

  pv_mfma<<<dim3(128), 256, 0, stream>>>(P, kv, qlen, klen, out);
}

// Round 15
// 43.443 us; speedup vs baseline: 1.0322x; 1.0322x over previous
//
#include <hip/hip_runtime.h>

#define NEGV (-10000000000.0f)

typedef unsigned short u16;
typedef _Float16 __attribute__((ext_vector_type(8))) f16x8;
typedef _Float16 __attribute__((ext_vector_type(4))) f16x4;
typedef __attribute__((ext_vector_type(4))) float f32x4;

__device__ __forceinline__ u16 f2fh(float f) {
  _Float16 h = (_Float16)f;
  return __builtin_bit_cast(u16, h);
}

__device__ __forceinline__ void gload16(const u16* g, u16* l) {
  __builtin_amdgcn_global_load_lds(
      (const __attribute__((address_space(1))) void*)g,
      (__attribute__((address_space(3))) void*)l, 16, 0, 0);
}

__device__ __forceinline__ f16x8 cvt8(float4 x, float4 y) {
  f16x8 o;
  o[0] = (_Float16)x.x; o[1] = (_Float16)x.y;
  o[2] = (_Float16)x.z; o[3] = (_Float16)x.w;
  o[4] = (_Float16)y.x; o[5] = (_Float16)y.y;
  o[6] = (_Float16)y.z; o[7] = (_Float16)y.w;
  return o;
}

// ---------------------------------------------------------------------------
// shared MFMA inner step: 64x64 tile in sA/sB ([row][64 fp16] = 128B rows,
// oct-granular XOR swizzle byte ^= (row&7)<<4), 4 waves (2x2), 2x2 fragments.
// ---------------------------------------------------------------------------
__device__ __forceinline__ void mfma_tile(const u16* sA, const u16* sB,
                                          int l, int wr, int wc,
                                          f32x4 (*acc)[2]) {
#pragma unroll
  for (int ks = 0; ks < 2; ks++) {
    f16x8 af[2], bfr[2];
#pragma unroll
    for (int f = 0; f < 2; f++) {
      int cb = (ks * 32 + ((l >> 4) << 3)) << 1;
      int row = wr * 32 + f * 16 + (l & 15);
      af[f] = *(const f16x8*)((const char*)sA + row * 128 + (cb ^ ((row & 7) << 4)));
      int col = wc * 32 + f * 16 + (l & 15);
      bfr[f] = *(const f16x8*)((const char*)sB + col * 128 + (cb ^ ((col & 7) << 4)));
    }
#pragma unroll
    for (int fm = 0; fm < 2; fm++)
#pragma unroll
      for (int fn = 0; fn < 2; fn++)
        acc[fm][fn] = __builtin_amdgcn_mfma_f32_16x16x32_f16(
            af[fm], bfr[fn], acc[fm][fn], 0, 0, 0);
  }
}

// ---------------------------------------------------------------------------
// dispatch 1: proj. XCD-swizzled (320 = 8x40, bijective). Masked tiles skip.
//   logical 0..63:  qpE = exp(2(query·Wq^T + b))  [1024][256]
//   logical 64..319: kpE = exp(2(Wk·kv[b]^T))     [b][256 a][512 k]
// f32 inputs, in-register fp16 convert into swizzled LDS, MFMA epilogue exp.
// ---------------------------------------------------------------------------
__global__ __launch_bounds__(256) void proj_mfma(
    const float* __restrict__ query, const float* __restrict__ kv,
    const float* __restrict__ W, const float* __restrict__ bias,
    const int* __restrict__ qlen_p, const int* __restrict__ klen_p,
    float* __restrict__ qpE, float* __restrict__ kpE)
{
  const int p = blockIdx.x;
  const int id = (p & 7) * 40 + (p >> 3);       // XCD-chunked logical id
  const int t = threadIdx.x;

  const float *A, *B; float* C;
  int lda, ldb, ldc, bm, bn;
  const float* bp = nullptr;
  if (id < 64) {
    bm = (id >> 2) * 64; bn = (id & 3) * 64;
    // skip fully-masked q-tile (64-row tile lies inside one 128-row batch)
    if ((bm & 127) >= qlen_p[bm >> 7]) return;
    A = query; lda = 512; B = W; ldb = 1024;
    C = qpE; ldc = 256;
    bp = bias;
  } else {
    int r = id - 64;
    int b = r >> 5, w5 = r & 31;
    bm = (w5 & 3) * 64; bn = (w5 >> 2) * 64;
    if (bn >= klen_p[b]) return;                // skip fully-masked k-tile
    A = W + 512; lda = 1024;
    B = kv + (size_t)b * 512 * 512; ldb = 512;
    C = kpE + (size_t)b * 256 * 512; ldc = 512;
  }

  __shared__ __align__(16) u16 sA[8 * 512];     // 64 rows x 64 fp16
  __shared__ __align__(16) u16 sB[8 * 512];

  const int l = t & 63, w = t >> 6;
  const int wr = w >> 1, wc = w & 1;
  const int r0 = t >> 3, oc = t & 7;
  const int sw0 = (oc * 16) ^ ((r0 & 7) << 4);

  f32x4 acc[2][2] = {};
  float4 a00, a01, a10, a11, b00, b01, b10, b11;

  auto LOAD = [&](int k0) {
    const float* pa0 = A + (size_t)(bm + r0) * lda + k0 + oc * 8;
    const float* pa1 = pa0 + (size_t)32 * lda;
    a00 = *(const float4*)pa0; a01 = *(const float4*)(pa0 + 4);
    a10 = *(const float4*)pa1; a11 = *(const float4*)(pa1 + 4);
    const float* pb0 = B + (size_t)(bn + r0) * ldb + k0 + oc * 8;
    const float* pb1 = pb0 + (size_t)32 * ldb;
    b00 = *(const float4*)pb0; b01 = *(const float4*)(pb0 + 4);
    b10 = *(const float4*)pb1; b11 = *(const float4*)(pb1 + 4);
  };
  auto WRITE = [&]() {
    *(f16x8*)((char*)sA + r0 * 128 + sw0)        = cvt8(a00, a01);
    *(f16x8*)((char*)sA + (r0 + 32) * 128 + sw0) = cvt8(a10, a11);
    *(f16x8*)((char*)sB + r0 * 128 + sw0)        = cvt8(b00, b01);
    *(f16x8*)((char*)sB + (r0 + 32) * 128 + sw0) = cvt8(b10, b11);
  };

  LOAD(0);
  for (int k0 = 0; k0 < 512; k0 += 64) {
    __syncthreads();
    WRITE();
    if (k0 + 64 < 512) LOAD(k0 + 64);
    __syncthreads();
    mfma_tile(sA, sB, l, wr, wc, acc);
  }

#pragma unroll
  for (int fm = 0; fm < 2; fm++)
#pragma unroll
    for (int fn = 0; fn < 2; fn++) {
      int cn = bn + wc * 32 + fn * 16 + (l & 15);
      float bv = bp ? bp[cn] : 0.0f;
#pragma unroll
      for (int j = 0; j < 4; j++) {
        int rm = bm + wr * 32 + fm * 16 + (l >> 4) * 4 + j;
        C[(size_t)rm * ldc + cn] = __expf((acc[fm][fn][j] + bv) * 2.0f);
      }
    }
}

// ---------------------------------------------------------------------------
// dispatch 2: fused score + softmax. 256 blocks XCD-swizzled so each batch's
// 32 blocks land on ONE XCD (kpE[b] = 512KB -> L2-resident). Block = 4 q rows
// x full 512 k (512 threads; lane owns k = t). a-loop unroll 16 for deeper
// load pipelining (~1 wave/SIMD here -> ILP must hide L2 latency).
// score'[q,k] = -sum_a 2 v_a / (1 + eq[q][a]*ek[a][k]) (softmax-equivalent).
// P fp16: masked q -> uniform 1/512; k>=klen -> exact 0.
// ---------------------------------------------------------------------------
__global__ __launch_bounds__(512) void score_softmax(
    const float* __restrict__ qpE,    // [B*128][256] = exp(2(qp+b))
    const float* __restrict__ kpE,    // [B][256][512] = exp(2kp)
    const float* __restrict__ v,      // [256]
    const int* __restrict__ qlen_p, const int* __restrict__ klen_p,
    u16* __restrict__ P)              // [B][128][512] fp16
{
  const int p = blockIdx.x;
  const int log = (p & 7) * 32 + (p >> 3);      // batch b entirely on XCD p&7
  const int b = log >> 5, q0 = (log & 31) * 4;
  const int t = threadIdx.x;
  const int qlen = qlen_p[b], klen = klen_p[b];
  const int w = t >> 6, l = t & 63;
  const int k = t;                    // 0..511
  u16* Pb = P + (size_t)(b * 128 + q0) * 512;

  if (q0 >= qlen) {                   // all 4 rows masked -> uniform 1/512
    const u16 uh = f2fh(1.0f / 512.0f);
#pragma unroll
    for (int r = 0; r < 4; r++) Pb[(size_t)r * 512 + k] = uh;
    return;
  }

  __shared__ float sEq[256][4];       // [a][row], uniform-broadcast reads
  __shared__ float sV2[256];
  __shared__ float sRed[8][8];        // [wave][r:max 0..3, r:sum 4..7]

  {
    int a = t & 255, rr = t >> 8;     // rr = 0,1
    sEq[a][rr]     = qpE[(size_t)(b * 128 + q0 + rr) * 256 + a];
    sEq[a][rr + 2] = qpE[(size_t)(b * 128 + q0 + rr + 2) * 256 + a];
    if (t < 256) sV2[t] = 2.0f * v[t];
  }
  __syncthreads();

  // ---- score ----
  float s[4] = {0.f, 0.f, 0.f, 0.f};
  if (w * 64 < klen) {                // wave has at least one active k
    const float* kc = kpE + (size_t)b * 256 * 512 + k;
#pragma unroll 16
    for (int a = 0; a < 256; a++) {
      float ek = kc[(size_t)a * 512];
      f32x4 eq = *(const f32x4*)&sEq[a][0];
      float vv = sV2[a];
#pragma unroll
      for (int r = 0; r < 4; r++)
        s[r] = fmaf(-vv, __builtin_amdgcn_rcpf(fmaf(eq[r], ek, 1.0f)), s[r]);
    }
  }
  if (k >= klen) {
#pragma unroll
    for (int r = 0; r < 4; r++) s[r] = NEGV;
  }

  // ---- softmax over 512 lanes (wave shuffle + 8-wave LDS combine) ----
#pragma unroll
  for (int r = 0; r < 4; r++) {
    float x = s[r];
#pragma unroll
    for (int off = 32; off > 0; off >>= 1) x = fmaxf(x, __shfl_xor(x, off));
    if (l == 0) sRed[w][r] = x;
  }
  __syncthreads();
  float e[4];
#pragma unroll
  for (int r = 0; r < 4; r++) {
    float mm = fmaxf(fmaxf(sRed[0][r], sRed[1][r]),
                     fmaxf(sRed[2][r], sRed[3][r]));
    mm = fmaxf(mm, fmaxf(fmaxf(sRed[4][r], sRed[5][r]),
                         fmaxf(sRed[6][r], sRed[7][r])));
    e[r] = __expf(s[r] - mm);         // k>=klen -> exact 0
  }
  __syncthreads();                    // sRed reuse
#pragma unroll
  for (int r = 0; r < 4; r++) {
    float x = e[r];
#pragma unroll
    for (int off = 32; off > 0; off >>= 1) x += __shfl_xor(x, off);
    if (l == 0) sRed[w][4 + r] = x;
  }
  __syncthreads();

  const u16 uh = f2fh(1.0f / 512.0f);
#pragma unroll
  for (int r = 0; r < 4; r++) {
    float S = (sRed[0][4 + r] + sRed[1][4 + r]) +
              (sRed[2][4 + r] + sRed[3][4 + r]) +
              (sRed[4][4 + r] + sRed[5][4 + r]) +
              (sRed[6][4 + r] + sRed[7][4 + r]);
    float pp = e[r] * __fdividef(1.0f, S);
    Pb[(size_t)r * 512 + k] = (q0 + r < qlen) ? f2fh(pp) : uh;
  }
}

// ---------------------------------------------------------------------------
// dispatch 3: pv. out[b] = P[b](fp16) @ kv[b](f32). 128 blocks XCD-swizzled:
// exactly one batch per XCD (kv[b]+P[b] L2-resident). kv tile transposed to
// [d][k] fp16 in LDS during staging; P staged via global_load_lds.
// k-loop trimmed to ceil(klen/64)*64 when all 64 q-rows of this block are
// active (P beyond klen is exact 0); blocks with masked q rows (uniform P)
// keep the full 512 loop.
// ---------------------------------------------------------------------------
__global__ __launch_bounds__(256) void pv_mfma(
    const u16* __restrict__ P, const float* __restrict__ kv,
    const int* __restrict__ qlen_p, const int* __restrict__ klen_p,
    float* __restrict__ out)
{
  __shared__ __align__(16) u16 sA[8 * 512];
  __shared__ __align__(16) u16 sB[8 * 512];
  const int p = blockIdx.x;
  const int log = (p & 7) * 16 + (p >> 3);      // one batch per XCD
  const int t = threadIdx.x;
  const int b = log >> 4, r = log & 15;
  const int bm = (r >> 3) * 64, bn = (r & 7) * 64;

  const int qlen = qlen_p[b], klen = klen_p[b];
  const int nk = (bm + 64 <= qlen) ? ((klen + 63) & ~63) : 512;

  const u16* Ab = P + (size_t)b * 128 * 512;
  const float* Bb = kv + (size_t)b * 512 * 512;

  const int l = t & 63, w = t >> 6;
  const int wr = w >> 1, wc = w & 1;
  const int srow = l >> 3, scol = ((l & 7) ^ srow) << 3;

  const int dq = t & 15, kq = t >> 4;

  float4 v0, v1, v2, v3;
  auto LOADB = [&](int k0) {
    const float* pp = Bb + (size_t)(k0 + kq * 4) * 512 + bn + dq * 4;
    v0 = *(const float4*)pp;
    v1 = *(const float4*)(pp + 512);
    v2 = *(const float4*)(pp + 1024);
    v3 = *(const float4*)(pp + 1536);
  };
  auto WRITEB = [&]() {
#define WRB(jj, ee)                                                       \
    { int d = dq * 4 + jj;                                                \
      f16x4 c; c[0] = (_Float16)v0.ee; c[1] = (_Float16)v1.ee;            \
      c[2] = (_Float16)v2.ee; c[3] = (_Float16)v3.ee;                     \
      *(f16x4*)((char*)sB + d * 128 +                                     \
                ((((kq >> 1) * 16) ^ ((d & 7) << 4)) + (kq & 1) * 8)) = c; }
    WRB(0, x) WRB(1, y) WRB(2, z) WRB(3, w)
#undef WRB
  };

  f32x4 acc[2][2] = {};
  LOADB(0);
  for (int k0 = 0; k0 < nk; k0 += 64) {
    __syncthreads();
    WRITEB();
#pragma unroll
    for (int i = 0; i < 2; i++) {
      int s = w * 2 + i;
      gload16(Ab + (size_t)(bm + s * 8 + srow) * 512 + k0 + scol, sA + s * 512);
    }
    if (k0 + 64 < nk) LOADB(k0 + 64);
    __syncthreads();
    mfma_tile(sA, sB, l, wr, wc, acc);
  }

  float* Cb = out + (size_t)b * 128 * 512;
#pragma unroll
  for (int fm = 0; fm < 2; fm++)
#pragma unroll
    for (int fn = 0; fn < 2; fn++) {
      int cn = bn + wc * 32 + fn * 16 + (l & 15);
#pragma unroll
      for (int j = 0; j < 4; j++) {
        int rm = bm + wr * 32 + fm * 16 + (l >> 4) * 4 + j;
        Cb[(size_t)rm * 512 + cn] = acc[fm][fn][j];
      }
    }
}

// ---------------------------------------------------------------------------
extern "C" void kernel_launch(void* const* d_in, const int* in_sizes, int n_in,
                              void* d_out, int out_size, void* d_ws, size_t ws_size,
                              hipStream_t stream)
{
  const float* query = (const float*)d_in[0];  // [8][128][512]
  const float* kv    = (const float*)d_in[1];  // [8][512][512]
  const float* W     = (const float*)d_in[2];  // [256][1024]
  const float* bbias = (const float*)d_in[3];  // [256]
  const float* v     = (const float*)d_in[4];  // [256]
  const int*   qlen  = (const int*)d_in[5];    // [8]
  const int*   klen  = (const int*)d_in[6];    // [8]
  float* out = (float*)d_out;                  // [8][128][512]

  float* qpE = (float*)d_ws;                   // 1MB
  float* kpE = qpE + 1024 * 256;               // 4MB
  u16*   P   = (u16*)(kpE + 8 * 256 * 512);    // 1MB

  proj_mfma<<<dim3(320), 256, 0, stream>>>(
      query, kv, W, bbias, qlen, klen, qpE, kpE);

  score_softmax<<<dim3(256), 512, 0, stream>>>(
      qpE, kpE, v, qlen, klen, P);

  pv_mfma<<<dim3(128), 256, 0, stream>>>(P, kv, qlen, klen, out);
}

// Round 16
// 40.394 us; speedup vs baseline: 1.1102x; 1.0755x over previous
//
#include <hip/hip_runtime.h>

#define NEGV (-10000000000.0f)

typedef unsigned short u16;
typedef _Float16 __attribute__((ext_vector_type(8))) f16x8;
typedef _Float16 __attribute__((ext_vector_type(4))) f16x4;
typedef __attribute__((ext_vector_type(4))) float f32x4;

__device__ __forceinline__ u16 f2fh(float f) {
  _Float16 h = (_Float16)f;
  return __builtin_bit_cast(u16, h);
}

__device__ __forceinline__ void gload16(const u16* g, u16* l) {
  __builtin_amdgcn_global_load_lds(
      (const __attribute__((address_space(1))) void*)g,
      (__attribute__((address_space(3))) void*)l, 16, 0, 0);
}

__device__ __forceinline__ f16x8 cvt8(float4 x, float4 y) {
  f16x8 o;
  o[0] = (_Float16)x.x; o[1] = (_Float16)x.y;
  o[2] = (_Float16)x.z; o[3] = (_Float16)x.w;
  o[4] = (_Float16)y.x; o[5] = (_Float16)y.y;
  o[6] = (_Float16)y.z; o[7] = (_Float16)y.w;
  return o;
}

// ---------------------------------------------------------------------------
// shared MFMA inner step: 64x64 tile in sA/sB ([row][64 fp16] = 128B rows,
// oct-granular XOR swizzle byte ^= (row&7)<<4), 4 waves (2x2), 2x2 fragments.
// ---------------------------------------------------------------------------
__device__ __forceinline__ void mfma_tile(const u16* sA, const u16* sB,
                                          int l, int wr, int wc,
                                          f32x4 (*acc)[2]) {
#pragma unroll
  for (int ks = 0; ks < 2; ks++) {
    f16x8 af[2], bfr[2];
#pragma unroll
    for (int f = 0; f < 2; f++) {
      int cb = (ks * 32 + ((l >> 4) << 3)) << 1;
      int row = wr * 32 + f * 16 + (l & 15);
      af[f] = *(const f16x8*)((const char*)sA + row * 128 + (cb ^ ((row & 7) << 4)));
      int col = wc * 32 + f * 16 + (l & 15);
      bfr[f] = *(const f16x8*)((const char*)sB + col * 128 + (cb ^ ((col & 7) << 4)));
    }
#pragma unroll
    for (int fm = 0; fm < 2; fm++)
#pragma unroll
      for (int fn = 0; fn < 2; fn++)
        acc[fm][fn] = __builtin_amdgcn_mfma_f32_16x16x32_f16(
            af[fm], bfr[fn], acc[fm][fn], 0, 0, 0);
  }
}

// ---------------------------------------------------------------------------
// dispatch 1: proj. XCD-swizzled (320 = 8x40, bijective). Masked tiles skip.
//   logical 0..63:  qpE = exp(2(query·Wq^T + b))  [1024][256]
//   logical 64..319: kpE = exp(2(Wk·kv[b]^T))     [b][256 a][512 k]
// f32 inputs, in-register fp16 convert into swizzled LDS, MFMA epilogue exp.
// ---------------------------------------------------------------------------
__global__ __launch_bounds__(256) void proj_mfma(
    const float* __restrict__ query, const float* __restrict__ kv,
    const float* __restrict__ W, const float* __restrict__ bias,
    const int* __restrict__ qlen_p, const int* __restrict__ klen_p,
    float* __restrict__ qpE, float* __restrict__ kpE)
{
  const int p = blockIdx.x;
  const int id = (p & 7) * 40 + (p >> 3);       // XCD-chunked logical id
  const int t = threadIdx.x;

  const float *A, *B; float* C;
  int lda, ldb, ldc, bm, bn;
  const float* bp = nullptr;
  if (id < 64) {
    bm = (id >> 2) * 64; bn = (id & 3) * 64;
    // skip fully-masked q-tile (64-row tile lies inside one 128-row batch)
    if ((bm & 127) >= qlen_p[bm >> 7]) return;
    A = query; lda = 512; B = W; ldb = 1024;
    C = qpE; ldc = 256;
    bp = bias;
  } else {
    int r = id - 64;
    int b = r >> 5, w5 = r & 31;
    bm = (w5 & 3) * 64; bn = (w5 >> 2) * 64;
    if (bn >= klen_p[b]) return;                // skip fully-masked k-tile
    A = W + 512; lda = 1024;
    B = kv + (size_t)b * 512 * 512; ldb = 512;
    C = kpE + (size_t)b * 256 * 512; ldc = 512;
  }

  __shared__ __align__(16) u16 sA[8 * 512];     // 64 rows x 64 fp16
  __shared__ __align__(16) u16 sB[8 * 512];

  const int l = t & 63, w = t >> 6;
  const int wr = w >> 1, wc = w & 1;
  const int r0 = t >> 3, oc = t & 7;
  const int sw0 = (oc * 16) ^ ((r0 & 7) << 4);

  f32x4 acc[2][2] = {};
  float4 a00, a01, a10, a11, b00, b01, b10, b11;

  auto LOAD = [&](int k0) {
    const float* pa0 = A + (size_t)(bm + r0) * lda + k0 + oc * 8;
    const float* pa1 = pa0 + (size_t)32 * lda;
    a00 = *(const float4*)pa0; a01 = *(const float4*)(pa0 + 4);
    a10 = *(const float4*)pa1; a11 = *(const float4*)(pa1 + 4);
    const float* pb0 = B + (size_t)(bn + r0) * ldb + k0 + oc * 8;
    const float* pb1 = pb0 + (size_t)32 * ldb;
    b00 = *(const float4*)pb0; b01 = *(const float4*)(pb0 + 4);
    b10 = *(const float4*)pb1; b11 = *(const float4*)(pb1 + 4);
  };
  auto WRITE = [&]() {
    *(f16x8*)((char*)sA + r0 * 128 + sw0)        = cvt8(a00, a01);
    *(f16x8*)((char*)sA + (r0 + 32) * 128 + sw0) = cvt8(a10, a11);
    *(f16x8*)((char*)sB + r0 * 128 + sw0)        = cvt8(b00, b01);
    *(f16x8*)((char*)sB + (r0 + 32) * 128 + sw0) = cvt8(b10, b11);
  };

  LOAD(0);
  for (int k0 = 0; k0 < 512; k0 += 64) {
    __syncthreads();
    WRITE();
    if (k0 + 64 < 512) LOAD(k0 + 64);
    __syncthreads();
    mfma_tile(sA, sB, l, wr, wc, acc);
  }

#pragma unroll
  for (int fm = 0; fm < 2; fm++)
#pragma unroll
    for (int fn = 0; fn < 2; fn++) {
      int cn = bn + wc * 32 + fn * 16 + (l & 15);
      float bv = bp ? bp[cn] : 0.0f;
#pragma unroll
      for (int j = 0; j < 4; j++) {
        int rm = bm + wr * 32 + fm * 16 + (l >> 4) * 4 + j;
        C[(size_t)rm * ldc + cn] = __expf((acc[fm][fn][j] + bv) * 2.0f);
      }
    }
}

// ---------------------------------------------------------------------------
// dispatch 2: fused score + softmax. 256 blocks XCD-swizzled so each batch's
// 32 blocks land on ONE XCD (kpE[b] = 512KB -> L2-resident). Block = 4 q rows
// x full 512 k (512 threads; lane owns k = t).
// score'[q,k] = -sum_a 2 v_a / (1 + eq[q][a]*ek[a][k]) (softmax-equivalent).
// P fp16: masked q -> uniform 1/512; k>=klen -> exact 0.
// ---------------------------------------------------------------------------
__global__ __launch_bounds__(512) void score_softmax(
    const float* __restrict__ qpE,    // [B*128][256] = exp(2(qp+b))
    const float* __restrict__ kpE,    // [B][256][512] = exp(2kp)
    const float* __restrict__ v,      // [256]
    const int* __restrict__ qlen_p, const int* __restrict__ klen_p,
    u16* __restrict__ P)              // [B][128][512] fp16
{
  const int p = blockIdx.x;
  const int log = (p & 7) * 32 + (p >> 3);      // batch b entirely on XCD p&7
  const int b = log >> 5, q0 = (log & 31) * 4;
  const int t = threadIdx.x;
  const int qlen = qlen_p[b], klen = klen_p[b];
  const int w = t >> 6, l = t & 63;
  const int k = t;                    // 0..511
  u16* Pb = P + (size_t)(b * 128 + q0) * 512;

  if (q0 >= qlen) {                   // all 4 rows masked -> uniform 1/512
    const u16 uh = f2fh(1.0f / 512.0f);
#pragma unroll
    for (int r = 0; r < 4; r++) Pb[(size_t)r * 512 + k] = uh;
    return;
  }

  __shared__ float sEq[256][4];       // [a][row], uniform-broadcast reads
  __shared__ float sV2[256];
  __shared__ float sRed[8][8];        // [wave][r:max 0..3, r:sum 4..7]

  {
    int a = t & 255, rr = t >> 8;     // rr = 0,1
    sEq[a][rr]     = qpE[(size_t)(b * 128 + q0 + rr) * 256 + a];
    sEq[a][rr + 2] = qpE[(size_t)(b * 128 + q0 + rr + 2) * 256 + a];
    if (t < 256) sV2[t] = 2.0f * v[t];
  }
  __syncthreads();

  // ---- score ----
  float s[4] = {0.f, 0.f, 0.f, 0.f};
  if (w * 64 < klen) {                // wave has at least one active k
    const float* kc = kpE + (size_t)b * 256 * 512 + k;
#pragma unroll 8
    for (int a = 0; a < 256; a++) {
      float ek = kc[(size_t)a * 512];
      f32x4 eq = *(const f32x4*)&sEq[a][0];
      float vv = sV2[a];
#pragma unroll
      for (int r = 0; r < 4; r++)
        s[r] = fmaf(-vv, __builtin_amdgcn_rcpf(fmaf(eq[r], ek, 1.0f)), s[r]);
    }
  }
  if (k >= klen) {
#pragma unroll
    for (int r = 0; r < 4; r++) s[r] = NEGV;
  }

  // ---- softmax over 512 lanes (wave shuffle + 8-wave LDS combine) ----
#pragma unroll
  for (int r = 0; r < 4; r++) {
    float x = s[r];
#pragma unroll
    for (int off = 32; off > 0; off >>= 1) x = fmaxf(x, __shfl_xor(x, off));
    if (l == 0) sRed[w][r] = x;
  }
  __syncthreads();
  float e[4];
#pragma unroll
  for (int r = 0; r < 4; r++) {
    float mm = fmaxf(fmaxf(sRed[0][r], sRed[1][r]),
                     fmaxf(sRed[2][r], sRed[3][r]));
    mm = fmaxf(mm, fmaxf(fmaxf(sRed[4][r], sRed[5][r]),
                         fmaxf(sRed[6][r], sRed[7][r])));
    e[r] = __expf(s[r] - mm);         // k>=klen -> exact 0
  }
  __syncthreads();                    // sRed reuse
#pragma unroll
  for (int r = 0; r < 4; r++) {
    float x = e[r];
#pragma unroll
    for (int off = 32; off > 0; off >>= 1) x += __shfl_xor(x, off);
    if (l == 0) sRed[w][4 + r] = x;
  }
  __syncthreads();

  const u16 uh = f2fh(1.0f / 512.0f);
#pragma unroll
  for (int r = 0; r < 4; r++) {
    float S = (sRed[0][4 + r] + sRed[1][4 + r]) +
              (sRed[2][4 + r] + sRed[3][4 + r]) +
              (sRed[4][4 + r] + sRed[5][4 + r]) +
              (sRed[6][4 + r] + sRed[7][4 + r]);
    float pp = e[r] * __fdividef(1.0f, S);
    Pb[(size_t)r * 512 + k] = (q0 + r < qlen) ? f2fh(pp) : uh;
  }
}

// ---------------------------------------------------------------------------
// dispatch 3: pv. out[b] = P[b](fp16) @ kv[b](f32). 128 blocks XCD-swizzled:
// exactly one batch per XCD (kv[b]+P[b] L2-resident). kv tile transposed to
// [d][k] fp16 in LDS during staging; P staged via global_load_lds.
// ---------------------------------------------------------------------------
__global__ __launch_bounds__(256) void pv_mfma(
    const u16* __restrict__ P, const float* __restrict__ kv,
    float* __restrict__ out)
{
  __shared__ __align__(16) u16 sA[8 * 512];
  __shared__ __align__(16) u16 sB[8 * 512];
  const int p = blockIdx.x;
  const int log = (p & 7) * 16 + (p >> 3);      // one batch per XCD
  const int t = threadIdx.x;
  const int b = log >> 4, r = log & 15;
  const int bm = (r >> 3) * 64, bn = (r & 7) * 64;

  const u16* Ab = P + (size_t)b * 128 * 512;
  const float* Bb = kv + (size_t)b * 512 * 512;

  const int l = t & 63, w = t >> 6;
  const int wr = w >> 1, wc = w & 1;
  const int srow = l >> 3, scol = ((l & 7) ^ srow) << 3;

  const int dq = t & 15, kq = t >> 4;

  float4 v0, v1, v2, v3;
  auto LOADB = [&](int k0) {
    const float* pp = Bb + (size_t)(k0 + kq * 4) * 512 + bn + dq * 4;
    v0 = *(const float4*)pp;
    v1 = *(const float4*)(pp + 512);
    v2 = *(const float4*)(pp + 1024);
    v3 = *(const float4*)(pp + 1536);
  };
  auto WRITEB = [&]() {
#define WRB(jj, ee)                                                       \
    { int d = dq * 4 + jj;                                                \
      f16x4 c; c[0] = (_Float16)v0.ee; c[1] = (_Float16)v1.ee;            \
      c[2] = (_Float16)v2.ee; c[3] = (_Float16)v3.ee;                     \
      *(f16x4*)((char*)sB + d * 128 +                                     \
                ((((kq >> 1) * 16) ^ ((d & 7) << 4)) + (kq & 1) * 8)) = c; }
    WRB(0, x) WRB(1, y) WRB(2, z) WRB(3, w)
#undef WRB
  };

  f32x4 acc[2][2] = {};
  LOADB(0);
  for (int k0 = 0; k0 < 512; k0 += 64) {
    __syncthreads();
    WRITEB();
#pragma unroll
    for (int i = 0; i < 2; i++) {
      int s = w * 2 + i;
      gload16(Ab + (size_t)(bm + s * 8 + srow) * 512 + k0 + scol, sA + s * 512);
    }
    if (k0 + 64 < 512) LOADB(k0 + 64);
    __syncthreads();
    mfma_tile(sA, sB, l, wr, wc, acc);
  }

  float* Cb = out + (size_t)b * 128 * 512;
#pragma unroll
  for (int fm = 0; fm < 2; fm++)
#pragma unroll
    for (int fn = 0; fn < 2; fn++) {
      int cn = bn + wc * 32 + fn * 16 + (l & 15);
#pragma unroll
      for (int j = 0; j < 4; j++) {
        int rm = bm + wr * 32 + fm * 16 + (l >> 4) * 4 + j;
        Cb[(size_t)rm * 512 + cn] = acc[fm][fn][j];
      }
    }
}

// ---------------------------------------------------------------------------
extern "C" void kernel_launch(void* const* d_in, const int* in_sizes, int n_in,
                              void* d_out, int out_size, void* d_ws, size_t ws_size,
                              hipStream_t stream)
{
  const float* query = (const float*)d_in[0];  // [8][128][512]
  const float* kv    = (const float*)d_in[1];  // [8][512][512]
  const float* W     = (const float*)d_in[2];  // [256][1024]
  const float* bbias = (const float*)d_in[3];  // [256]
  const float* v     = (const float*)d_in[4];  // [256]
  const int*   qlen  = (const int*)d_in[5];    // [8]
  const int*   klen  = (const int*)d_in[6];    // [8]
  float* out = (float*)d_out;                  // [8][128][512]

  float* qpE = (float*)d_ws;                   // 1MB
  float* kpE = qpE + 1024 * 256;               // 4MB
  u16*   P   = (u16*)(kpE + 8 * 256 * 512);    // 1MB

  proj_mfma<<<dim3(320), 256, 0, stream>>>(
      query, kv, W, bbias, qlen, klen, qpE, kpE);

  score_softmax<<<dim3(256), 512, 0, stream>>>(
      qpE, kpE, v, qlen, klen, P);

  pv_mfma<<<dim3(128), 256, 0, stream>>>(P, kv, out);
}